// Round 1
// 284.589 us; speedup vs baseline: 1.0974x; 1.0974x over previous
//
#include <hip/hip_runtime.h>

#define NN 50000
#define NE 800000
#define D 128
#define NEG 0.2f

#define NBLK1 256        // pass-1 blocks
#define TILE1 3125       // NE / NBLK1 (exact)
#define NB2 196          // coarse buckets (dst>>8)
#define CAP2 8192        // max edges per coarse bucket
#define NT64 782         // ceil(NN/64) row tiles

// setup kernel block ranges
#define SB_PREP 576              // 9 matrices x 64 blocks
#define SB_CONV 6250             // NN*D/4/256
#define SB_HIST NBLK1
#define SB_TOTAL (SB_PREP + SB_CONV + SB_HIST)

typedef short bf8_t __attribute__((ext_vector_type(8)));   // 8 x bf16 (16 B)
typedef float f4_t __attribute__((ext_vector_type(4)));

__device__ __forceinline__ unsigned short f2bf(float f) {
  unsigned int u = __float_as_uint(f);
  return (unsigned short)((u + 0x7FFF + ((u >> 16) & 1)) >> 16);  // RNE
}
__device__ __forceinline__ float bf2f(unsigned int b) { return __uint_as_float(b << 16); }

__device__ __forceinline__ f4_t MF(bf8_t a, bf8_t b, f4_t c) {
  return __builtin_amdgcn_mfma_f32_16x16x32_bf16(a, b, c, 0, 0, 0);
}

// LDS tile swizzle: 16B unit u, row = u>>4 (16 units per 128-col bf16 row).
// XOR row's low 3 bits into the unit index -> 16 l15-lanes spread over all
// 8 bank-quads instead of 4 -> ds_read_b128 at the 8-beat floor.
__device__ __forceinline__ int swz_u(int u) { return u ^ ((u >> 4) & 7); }

// ---------------- GEMM building blocks (64-row tile, 4 waves, 16 rows/wave) ----------

__device__ __forceinline__ void stage_w(unsigned short* wbuf,
                                        const unsigned short* __restrict__ WT, int t) {
#pragma unroll
  for (int i = 0; i < 8; ++i) {
    int u = t + i * 256;
    *(uint4*)(wbuf + swz_u(u) * 8) = *(const uint4*)(WT + u * 8);
  }
}

__device__ __forceinline__ void load_a16(const unsigned short* __restrict__ A,
                                         int base, int l15, int quad, bf8_t (&afr)[4]) {
  int r = base + l15;
  if (r >= NN) r = NN - 1;
  const unsigned short* p = A + (size_t)r * D + quad * 8;
#pragma unroll
  for (int kc = 0; kc < 4; ++kc) afr[kc] = *(const bf8_t*)(p + kc * 32);
}

// A-fragments from a swizzled 64x128 LDS tile
__device__ __forceinline__ void load_a16_lds(const unsigned short* buf, int wave,
                                             int l15, int quad, bf8_t (&afr)[4]) {
  const int r = wave * 16 + l15;
#pragma unroll
  for (int kc = 0; kc < 4; ++kc)
    afr[kc] = *(const bf8_t*)(buf + swz_u(r * 16 + kc * 4 + quad) * 8);
}

__device__ __forceinline__ void tile16(const unsigned short* wbuf, const bf8_t (&afr)[4],
                                       int l15, int quad, f4_t (&acc)[8]) {
#pragma unroll
  for (int kc = 0; kc < 4; ++kc)
#pragma unroll
    for (int nt = 0; nt < 8; ++nt) {
      bf8_t b = *(const bf8_t*)(wbuf + swz_u((nt * 16 + l15) * 16 + kc * 4 + quad) * 8);
      acc[nt] = MF(afr[kc], b, acc[nt]);
    }
}

__device__ __forceinline__ void store_c(unsigned short* __restrict__ C,
                                        const float* __restrict__ bias,
                                        const f4_t (&acc)[8], int base, int l15, int quad,
                                        bool lk) {
#pragma unroll
  for (int nt = 0; nt < 8; ++nt) {
    int col = nt * 16 + l15;
    float bb = bias[col];
#pragma unroll
    for (int reg = 0; reg < 4; ++reg) {
      int row = base + quad * 4 + reg;
      if (row < NN) {
        float v = acc[nt][reg] + bb;
        if (lk) v = v >= 0.f ? v : NEG * v;
        C[(size_t)row * D + col] = f2bf(v);
      }
    }
  }
}

// ---------------- setup: weight prep + feats convert + coarse histogram --------------
__global__ __launch_bounds__(256) void setup(
    const float* __restrict__ Wq, const float* __restrict__ Wk,
    const float* __restrict__ Wr, const float* __restrict__ Wro,
    const float* __restrict__ feats, const int* __restrict__ dst,
    unsigned short* __restrict__ WT, unsigned short* __restrict__ x0,
    int* __restrict__ H) {
  __shared__ int cnt[NB2];
  const int b = blockIdx.x;
  const int t = threadIdx.x;
  if (b < SB_PREP) {
    const int m = b >> 6, xb = b & 63;
    const float* src;
    if (m < 2) src = Wq + m * D * D;
    else if (m < 4) src = Wk + (m - 2) * D * D;
    else if (m < 6) src = Wr + (m - 4) * D * D;
    else src = Wro + (m - 6) * D * D;
    const int n = xb * 2 + (t >> 7);
    const int k = t & 127;
    WT[(size_t)m * D * D + n * D + k] = f2bf(src[k * D + n]);
  } else if (b < SB_PREP + SB_CONV) {
    int i = ((b - SB_PREP) * 256 + t) * 4;
    float4 v = *(const float4*)(feats + i);
    ushort4 o = {f2bf(v.x), f2bf(v.y), f2bf(v.z), f2bf(v.w)};
    *(ushort4*)(x0 + i) = o;
  } else {
    const int blk = b - SB_PREP - SB_CONV;
    if (t < NB2) cnt[t] = 0;
    __syncthreads();
    const int beg = blk * TILE1, end = beg + TILE1;
    for (int i = beg + t; i < end; i += 256) atomicAdd(&cnt[dst[i] >> 8], 1);
    __syncthreads();
    if (t < NB2) H[t * NBLK1 + blk] = cnt[t];
  }
}

// ---------------- p1_scan: per-bin block computes its own base + row scan ------------
__global__ __launch_bounds__(256) void p1_scan(const int* __restrict__ H,
                                               int* __restrict__ gofs) {
  __shared__ int sd[256];
  __shared__ int wsum[4];
  const int bin = blockIdx.x;
  const int t = threadIdx.x;
  const int wave = t >> 6, lane = t & 63;
  // base = sum of all earlier bins' totals
  int part = 0;
  for (int b2 = 0; b2 < bin; ++b2) part += H[b2 * NBLK1 + t];
  for (int off = 32; off; off >>= 1) part += __shfl_down(part, off, 64);
  if (lane == 0) wsum[wave] = part;
  __syncthreads();
  const int base = wsum[0] + wsum[1] + wsum[2] + wsum[3];
  // exclusive scan of own row
  int x = H[bin * NBLK1 + t];
  sd[t] = x;
  __syncthreads();
  int acc = x;
  for (int off = 1; off < 256; off <<= 1) {
    int y = (t >= off) ? sd[t - off] : 0;
    __syncthreads();
    acc += y;
    sd[t] = acc;
    __syncthreads();
  }
  gofs[bin * NBLK1 + t] = base + (acc - x);
}

__global__ __launch_bounds__(256) void p1_scatter(const int* __restrict__ src,
                                                  const int* __restrict__ dst,
                                                  const int* __restrict__ gofs,
                                                  unsigned int* __restrict__ ebuf) {
  __shared__ int lofs[NB2];
  const int t = threadIdx.x;
  const int blk = blockIdx.x;
  if (t < NB2) lofs[t] = gofs[t * NBLK1 + blk];
  __syncthreads();
  const int beg = blk * TILE1, end = beg + TILE1;
  for (int i = beg + t; i < end; i += 256) {
    unsigned int d = (unsigned int)dst[i];
    int pos = atomicAdd(&lofs[d >> 8], 1);
    ebuf[pos] = (unsigned int)src[i] | (d << 16);
  }
}

// ---------------- merged: p2 counting sort (196 blocks) + layer-0 QK GEMM ------------
__global__ __launch_bounds__(256) void sort_qk0(
    const int* __restrict__ gofs, const unsigned int* __restrict__ ebuf,
    int* __restrict__ ssrc, int* __restrict__ rowptr, int* __restrict__ deg,
    const unsigned short* __restrict__ x0,
    const unsigned short* __restrict__ WTq, const float* __restrict__ bq_,
    const unsigned short* __restrict__ WTk, const float* __restrict__ bk_,
    unsigned short* __restrict__ hq, unsigned short* __restrict__ hk) {
  __shared__ __align__(16) unsigned char smraw[35840];  // max(sort 35KB, wbuf 32KB)
  const int t = threadIdx.x;
  const int gx = blockIdx.x;
  if (gx < NB2) {
    int* cnt = (int*)smraw;
    int* fill = cnt + 256;
    int* sd = fill + 256;
    unsigned int* sorted = (unsigned int*)(sd + 256);
    const int b = gx;
    const int beg = gofs[b * NBLK1];
    const int end = (b + 1 < NB2) ? gofs[(b + 1) * NBLK1] : NE;
    const int n = end - beg;
    cnt[t] = 0;
    __syncthreads();
    for (int i = beg + t; i < end; i += 256)
      atomicAdd(&cnt[(ebuf[i] >> 16) & 255], 1);
    __syncthreads();
    int x = cnt[t];
    sd[t] = x;
    __syncthreads();
    int acc = x;
    for (int off = 1; off < 256; off <<= 1) {
      int y = (t >= off) ? sd[t - off] : 0;
      __syncthreads();
      acc += y;
      sd[t] = acc;
      __syncthreads();
    }
    const int excl = acc - x;
    fill[t] = excl;
    __syncthreads();
    for (int i = beg + t; i < end; i += 256) {
      unsigned int p = ebuf[i];
      int pos = atomicAdd(&fill[(p >> 16) & 255], 1);
      if (pos < CAP2) sorted[pos] = p;
    }
    __syncthreads();
    for (int i = t; i < n; i += 256) ssrc[beg + i] = (int)(sorted[i] & 0xFFFFu);
    const int node = (b << 8) + t;
    if (node < NN) {
      rowptr[node] = beg + excl;
      deg[node] = x;
    }
    if (b == 0 && t == 0) rowptr[NN] = NE;
  } else {
    unsigned short* wbuf = (unsigned short*)smraw;
    const int g = gx - NB2;
    const int sel = g & 1, tile = g >> 1;
    const int wave = t >> 6, lane = t & 63;
    const int l15 = lane & 15, quad = lane >> 4;
    const int base = tile * 64 + wave * 16;
    stage_w(wbuf, sel ? WTk : WTq, t);
    bf8_t afr[4];
    load_a16(x0, base, l15, quad, afr);
    __syncthreads();
    f4_t acc[8] = {};
    tile16(wbuf, afr, l15, quad, acc);
    store_c(sel ? hk : hq, sel ? bk_ : bq_, acc, base, l15, quad, false);
  }
}

// ---------------- aggregation: wide gather, 16 loads in flight per wave --------------
#define PROC(kb)                                                     \
  {                                                                  \
    float m;                                                         \
    m = q[0] + bf2f(kb.x & 0xFFFFu); a[0] += m >= 0.f ? m : NEG * m; \
    m = q[1] + bf2f(kb.x >> 16);     a[1] += m >= 0.f ? m : NEG * m; \
    m = q[2] + bf2f(kb.y & 0xFFFFu); a[2] += m >= 0.f ? m : NEG * m; \
    m = q[3] + bf2f(kb.y >> 16);     a[3] += m >= 0.f ? m : NEG * m; \
    m = q[4] + bf2f(kb.z & 0xFFFFu); a[4] += m >= 0.f ? m : NEG * m; \
    m = q[5] + bf2f(kb.z >> 16);     a[5] += m >= 0.f ? m : NEG * m; \
    m = q[6] + bf2f(kb.w & 0xFFFFu); a[6] += m >= 0.f ? m : NEG * m; \
    m = q[7] + bf2f(kb.w >> 16);     a[7] += m >= 0.f ? m : NEG * m; \
  }

__global__ __launch_bounds__(256) void aggregate(
    const int* __restrict__ rowptr, const int* __restrict__ ssrc,
    const int* __restrict__ deg,
    const unsigned short* __restrict__ hq, const unsigned short* __restrict__ hk,
    unsigned short* __restrict__ ag) {
  const int wave = threadIdx.x >> 6, lane = threadIdx.x & 63;
  const int v = blockIdx.x * 4 + wave;
  if (v >= NN) return;
  const int sub = lane & 15, grp = lane >> 4;
  const int beg = rowptr[v], end = rowptr[v + 1];

  uint4 qb = *(const uint4*)(hq + (size_t)v * D + sub * 8);
  float q[8];
  q[0] = bf2f(qb.x & 0xFFFFu); q[1] = bf2f(qb.x >> 16);
  q[2] = bf2f(qb.y & 0xFFFFu); q[3] = bf2f(qb.y >> 16);
  q[4] = bf2f(qb.z & 0xFFFFu); q[5] = bf2f(qb.z >> 16);
  q[6] = bf2f(qb.w & 0xFFFFu); q[7] = bf2f(qb.w >> 16);

  float a[8] = {0.f, 0.f, 0.f, 0.f, 0.f, 0.f, 0.f, 0.f};
  int e = beg + grp;
  for (; e + 12 < end; e += 16) {  // 4 edge streams -> 16 x 16B in flight per wave
    int s0 = ssrc[e];
    int s1 = ssrc[e + 4];
    int s2 = ssrc[e + 8];
    int s3 = ssrc[e + 12];
    uint4 k0 = *(const uint4*)(hk + (size_t)s0 * D + sub * 8);
    uint4 k1 = *(const uint4*)(hk + (size_t)s1 * D + sub * 8);
    uint4 k2 = *(const uint4*)(hk + (size_t)s2 * D + sub * 8);
    uint4 k3 = *(const uint4*)(hk + (size_t)s3 * D + sub * 8);
    PROC(k0);
    PROC(k1);
    PROC(k2);
    PROC(k3);
  }
  for (; e + 4 < end; e += 8) {    // pair tail
    int s0 = ssrc[e];
    int s1 = ssrc[e + 4];
    uint4 k0 = *(const uint4*)(hk + (size_t)s0 * D + sub * 8);
    uint4 k1 = *(const uint4*)(hk + (size_t)s1 * D + sub * 8);
    PROC(k0);
    PROC(k1);
  }
  if (e < end) {
    int s0 = ssrc[e];
    uint4 k0 = *(const uint4*)(hk + (size_t)s0 * D + sub * 8);
    PROC(k0);
  }
#pragma unroll
  for (int j = 0; j < 8; ++j) {
    a[j] += __shfl_xor(a[j], 16, 64);
    a[j] += __shfl_xor(a[j], 32, 64);
  }
  if (grp == 0) {
    float inv = 1.f / fmaxf((float)deg[v], 1.f);
    uint4 o;
    o.x = (unsigned int)f2bf(a[0] * inv) | ((unsigned int)f2bf(a[1] * inv) << 16);
    o.y = (unsigned int)f2bf(a[2] * inv) | ((unsigned int)f2bf(a[3] * inv) << 16);
    o.z = (unsigned int)f2bf(a[4] * inv) | ((unsigned int)f2bf(a[5] * inv) << 16);
    o.w = (unsigned int)f2bf(a[6] * inv) | ((unsigned int)f2bf(a[7] * inv) << 16);
    *(uint4*)(ag + (size_t)v * D + sub * 8) = o;
  }
}

// ---------------- fused: h1 = leaky(ag@Wr0 + br0); hq = h1@Wq1; hk = h1@Wk1 ----------
// h1 tile parked swizzled in LDS between phases; h1 written once (vectorized from LDS)
__global__ __launch_bounds__(256) void wr_qk1(
    const unsigned short* __restrict__ ag,
    const unsigned short* __restrict__ WTr, const float* __restrict__ brr,
    unsigned short* __restrict__ h1,
    const unsigned short* __restrict__ WTq, const float* __restrict__ bq1,
    unsigned short* __restrict__ hq,
    const unsigned short* __restrict__ WTk, const float* __restrict__ bk1,
    unsigned short* __restrict__ hk) {
  __shared__ unsigned short wbuf[D * D];   // 32 KB
  __shared__ unsigned short abuf[64 * D];  // 16 KB (swizzled h1 tile)
  const int t = threadIdx.x, wave = t >> 6, lane = t & 63;
  const int l15 = lane & 15, quad = lane >> 4;
  const int tb = blockIdx.x * 64;
  const int base = tb + wave * 16;

  // phase 0: h1 = leaky(ag @ Wr0 + br0)
  stage_w(wbuf, WTr, t);
  bf8_t afr[4];
  load_a16(ag, base, l15, quad, afr);
  __syncthreads();
  f4_t acc[8] = {};
  tile16(wbuf, afr, l15, quad, acc);
#pragma unroll
  for (int nt = 0; nt < 8; ++nt) {
    int col = nt * 16 + l15;
    float bb = brr[col];
#pragma unroll
    for (int reg = 0; reg < 4; ++reg) {
      int rl = wave * 16 + quad * 4 + reg;
      float v = acc[nt][reg] + bb;
      v = v >= 0.f ? v : NEG * v;
      int s = rl * D + col;
      abuf[s ^ ((rl & 7) << 3)] = f2bf(v);
    }
  }
  __syncthreads();  // abuf complete, wbuf free

  // write h1 to global, 16B vectors straight out of LDS
#pragma unroll
  for (int i = 0; i < 4; ++i) {
    int u = t + i * 256;
    int row = tb + (u >> 4);
    if (row < NN)
      *(uint4*)(h1 + (size_t)tb * D + u * 8) = *(const uint4*)(abuf + swz_u(u) * 8);
  }
  bf8_t hfr[4];
  load_a16_lds(abuf, wave, l15, quad, hfr);

  // phase 1: hq = h1 @ Wq1 + bq1
  stage_w(wbuf, WTq, t);
  __syncthreads();
  f4_t accq[8] = {};
  tile16(wbuf, hfr, l15, quad, accq);
  store_c(hq, bq1, accq, base, l15, quad, false);
  __syncthreads();

  // phase 2: hk = h1 @ Wk1 + bk1
  stage_w(wbuf, WTk, t);
  __syncthreads();
  f4_t acck[8] = {};
  tile16(wbuf, hfr, l15, quad, acck);
  store_c(hk, bk1, acck, base, l15, quad, false);
}

// ---------------- fused: h2 = leaky(ag@Wr1 + br1) (LDS only, never stored);
//                  out = x0@Wro0 + h1@Wro1 + h2@Wro2 + sum(bro) ----------------------
__global__ __launch_bounds__(256) void wr_ro(
    const unsigned short* __restrict__ ag,
    const unsigned short* __restrict__ WTr, const float* __restrict__ brr,
    const unsigned short* __restrict__ x0,
    const unsigned short* __restrict__ h1,
    const unsigned short* __restrict__ WTro, const float* __restrict__ bro_,
    float* __restrict__ out) {
  __shared__ unsigned short wbuf[D * D];   // 32 KB
  __shared__ unsigned short abuf[64 * D];  // 16 KB (swizzled h2 tile)
  const int t = threadIdx.x, wave = t >> 6, lane = t & 63;
  const int l15 = lane & 15, quad = lane >> 4;
  const int tb = blockIdx.x * 64;
  const int base = tb + wave * 16;

  // phase 0: h2 = leaky(ag @ Wr1 + br1) -> abuf
  stage_w(wbuf, WTr, t);
  bf8_t afr[4];
  load_a16(ag, base, l15, quad, afr);
  __syncthreads();
  f4_t acch[8] = {};
  tile16(wbuf, afr, l15, quad, acch);
#pragma unroll
  for (int nt = 0; nt < 8; ++nt) {
    int col = nt * 16 + l15;
    float bb = brr[col];
#pragma unroll
    for (int reg = 0; reg < 4; ++reg) {
      int rl = wave * 16 + quad * 4 + reg;
      float v = acch[nt][reg] + bb;
      v = v >= 0.f ? v : NEG * v;
      int s = rl * D + col;
      abuf[s ^ ((rl & 7) << 3)] = f2bf(v);
    }
  }
  __syncthreads();  // abuf complete, wbuf free

  bf8_t hfr[4];
  load_a16_lds(abuf, wave, l15, quad, hfr);
  f4_t acc[8] = {};

  // phase 1: acc += h2 @ Wro2
  stage_w(wbuf, WTro + 2 * (size_t)D * D, t);
  __syncthreads();
  tile16(wbuf, hfr, l15, quad, acc);
  __syncthreads();

  // phase 2: acc += x0 @ Wro0
  stage_w(wbuf, WTro, t);
  load_a16(x0, base, l15, quad, afr);
  __syncthreads();
  tile16(wbuf, afr, l15, quad, acc);
  __syncthreads();

  // phase 3: acc += h1 @ Wro1
  stage_w(wbuf, WTro + (size_t)D * D, t);
  load_a16(h1, base, l15, quad, afr);
  __syncthreads();
  tile16(wbuf, afr, l15, quad, acc);

#pragma unroll
  for (int nt = 0; nt < 8; ++nt) {
    int col = nt * 16 + l15;
    float bsum = bro_[col] + bro_[D + col] + bro_[2 * D + col];
#pragma unroll
    for (int reg = 0; reg < 4; ++reg) {
      int row = base + quad * 4 + reg;
      if (row < NN) out[(size_t)row * D + col] = acc[nt][reg] + bsum;
    }
  }
}

// ---------------- launch ----------------
extern "C" void kernel_launch(void* const* d_in, const int* in_sizes, int n_in,
                              void* d_out, int out_size, void* d_ws, size_t ws_size,
                              hipStream_t stream) {
  const float* feats = (const float*)d_in[0];
  const float* Wq = (const float*)d_in[1];
  const float* bq = (const float*)d_in[2];
  const float* Wk = (const float*)d_in[3];
  const float* bk = (const float*)d_in[4];
  const float* Wr = (const float*)d_in[5];
  const float* br = (const float*)d_in[6];
  const float* Wro = (const float*)d_in[7];
  const float* bro = (const float*)d_in[8];
  const int* src = (const int*)d_in[9];
  const int* dst = (const int*)d_in[10];
  float* out = (float*)d_out;

  size_t off = 0;
  char* base = (char*)d_ws;
  auto alloc = [&](size_t bytes) -> void* {
    void* p = base + off;
    off += (bytes + 255) & ~(size_t)255;
    return p;
  };
  int* H = (int*)alloc((size_t)NB2 * NBLK1 * 4);
  int* gofs = (int*)alloc((size_t)NB2 * NBLK1 * 4);
  unsigned int* ebuf = (unsigned int*)alloc((size_t)NE * 4);
  int* ssrc = (int*)alloc((size_t)NE * 4);
  int* rowptr = (int*)alloc((size_t)(NN + 1) * 4);
  int* deg = (int*)alloc((size_t)NN * 4);
  unsigned short* WT = (unsigned short*)alloc((size_t)9 * D * D * 2);
  unsigned short* x0 = (unsigned short*)alloc((size_t)NN * D * 2);
  unsigned short* hq = (unsigned short*)alloc((size_t)NN * D * 2);
  unsigned short* hk = (unsigned short*)alloc((size_t)NN * D * 2);
  unsigned short* ag = (unsigned short*)alloc((size_t)NN * D * 2);
  unsigned short* h1 = (unsigned short*)alloc((size_t)NN * D * 2);

  const size_t WM = (size_t)D * D;
  const int ab = (NN + 3) / 4;

  // 1: weights + feats-convert + coarse hist (independent, one dispatch)
  setup<<<SB_TOTAL, 256, 0, stream>>>(Wq, Wk, Wr, Wro, feats, dst, WT, x0, H);
  // 2: hierarchical offsets
  p1_scan<<<NB2, 256, 0, stream>>>(H, gofs);
  // 3: bucket scatter
  p1_scatter<<<NBLK1, 256, 0, stream>>>(src, dst, gofs, ebuf);
  // 4: per-bucket sort (196 blocks) overlapped with layer-0 QK GEMM (1564 blocks)
  sort_qk0<<<NB2 + 2 * NT64, 256, 0, stream>>>(gofs, ebuf, ssrc, rowptr, deg,
                                               x0, WT + 0 * WM, bq, WT + 2 * WM, bk,
                                               hq, hk);
  // 5: layer-0 aggregate
  aggregate<<<ab, 256, 0, stream>>>(rowptr, ssrc, deg, hq, hk, ag);
  // 6: fused h1 = leaky(ag@Wr0), hq/hk = h1@Wq1/Wk1
  wr_qk1<<<NT64, 256, 0, stream>>>(ag, WT + 4 * WM, br, h1,
                                   WT + 1 * WM, bq + D, hq,
                                   WT + 3 * WM, bk + D, hk);
  // 7: layer-1 aggregate
  aggregate<<<ab, 256, 0, stream>>>(rowptr, ssrc, deg, hq, hk, ag);
  // 8: fused h2 = leaky(ag@Wr1) (LDS only) + JK readout
  wr_ro<<<NT64, 256, 0, stream>>>(ag, WT + 5 * WM, br + D, x0, h1,
                                  WT + 6 * WM, bro, out);
}